// Round 1
// baseline (33921.881 us; speedup 1.0000x reference)
//
#include <hip/hip_runtime.h>
#include <hip/hip_bf16.h>

// GraphNet: B=64, N=128, H=32, HE=64, OE=32, E_IN=66, 4 message-passing steps.
// fp32 baseline. BN (training-mode, biased var) handled via two-pass stats.

#define B_SZ 64
#define N_ND 128
#define H_SZ 32
#define HE_SZ 64
#define OE_SZ 32
#define EIN 66
#define ALPHA 0.1f
#define BN_EPS 1e-5f

#define LRELU(v) ((v) > 0.f ? (v) : ALPHA * (v))

// ---------------- pad input [B,N,3] -> [B,N,32] ----------------
__global__ __launch_bounds__(256) void k_pad(const float* __restrict__ x,
                                             float* __restrict__ xc) {
    int idx = blockIdx.x * 256 + threadIdx.x;   // 262144 total
    int c = idx & 31;
    int bn = idx >> 5;
    xc[idx] = (c < 3) ? x[bn * 3 + c] : 0.f;
}

// ---------------- edge pass 1: stats of lrelu(A @ W1 + b1) ----------------
// grid: 512 blocks (64 b * 8 i-tiles of 16). 256 threads.
// thread: i_local = tid>>4, j0 = tid&15, edges j = j0 + e*16, e=0..7.
__global__ __launch_bounds__(256) void k_edge1(const float* __restrict__ xc,
                                               const float* __restrict__ W1,
                                               const float* __restrict__ b1,
                                               float* __restrict__ st) {
    __shared__ float w1s[EIN * HE_SZ];
    __shared__ float xs[N_ND * 33];
    __shared__ float bs[HE_SZ];
    __shared__ float red[4 * 128];
    const int tid = threadIdx.x;
    const int b = blockIdx.x >> 3;
    const int ibase = (blockIdx.x & 7) << 4;
    for (int k = tid; k < EIN * HE_SZ; k += 256) w1s[k] = W1[k];
    if (tid < HE_SZ) bs[tid] = b1[tid];
    const float* xg = xc + b * (N_ND * H_SZ);
#pragma unroll
    for (int r = 0; r < 16; ++r) {
        int f = r * 256 + tid;
        xs[(f >> 5) * 33 + (f & 31)] = xg[f];
    }
    __syncthreads();
    const int il = tid >> 4, j0 = tid & 15;
    float a[EIN];
    {
        const float* x1p = &xs[(ibase + il) * 33];
#pragma unroll
        for (int c = 0; c < 32; ++c) a[c] = x1p[c];
    }
    float sum[64], sq[64];
#pragma unroll
    for (int c = 0; c < 64; ++c) { sum[c] = 0.f; sq[c] = 0.f; }

    for (int e = 0; e < 8; ++e) {
        const float* x2p = &xs[(j0 + e * 16) * 33];
#pragma unroll
        for (int c = 0; c < 32; ++c) a[32 + c] = x2p[c];
        float ss = 0.f;
#pragma unroll
        for (int k = 0; k < 31; ++k) {
            float d = a[32 + k] - a[k] + 1e-12f;
            ss += d * d;
        }
        a[64] = sqrtf(ss);
        a[65] = 1.0f - (a[63] - a[31]);
#pragma unroll
        for (int c0 = 0; c0 < 64; c0 += 4) {
            float y0 = bs[c0], y1 = bs[c0 + 1], y2 = bs[c0 + 2], y3 = bs[c0 + 3];
#pragma unroll
            for (int k = 0; k < EIN; ++k) {
                const float4 w = *(const float4*)&w1s[k * 64 + c0];
                const float av = a[k];
                y0 = fmaf(av, w.x, y0);
                y1 = fmaf(av, w.y, y1);
                y2 = fmaf(av, w.z, y2);
                y3 = fmaf(av, w.w, y3);
            }
            y0 = LRELU(y0); y1 = LRELU(y1); y2 = LRELU(y2); y3 = LRELU(y3);
            sum[c0] += y0;     sq[c0] += y0 * y0;
            sum[c0 + 1] += y1; sq[c0 + 1] += y1 * y1;
            sum[c0 + 2] += y2; sq[c0 + 2] += y2 * y2;
            sum[c0 + 3] += y3; sq[c0 + 3] += y3 * y3;
        }
    }
    // wave butterfly reduce over 64 lanes
#pragma unroll
    for (int c = 0; c < 64; ++c) {
        float s = sum[c], q = sq[c];
#pragma unroll
        for (int m = 1; m < 64; m <<= 1) {
            s += __shfl_xor(s, m, 64);
            q += __shfl_xor(q, m, 64);
        }
        sum[c] = s; sq[c] = q;
    }
    const int lane = tid & 63, wid = tid >> 6;
    if (lane == 0) {
#pragma unroll
        for (int c = 0; c < 64; ++c) {
            red[wid * 128 + c] = sum[c];
            red[wid * 128 + 64 + c] = sq[c];
        }
    }
    __syncthreads();
    if (tid < 128) {
        float t = red[tid] + red[128 + tid] + red[256 + tid] + red[384 + tid];
        atomicAdd(&st[tid], t);
    }
}

// ---------------- edge pass 2: recompute, BN1, GEMM2, aggregate ----------------
// st2: [0..31] col-sums (filled later by k_sumagg), [32..63] sumsq (here)
__global__ __launch_bounds__(256) void k_edge2(const float* __restrict__ xc,
                                               const float* __restrict__ W1,
                                               const float* __restrict__ b1,
                                               const float* __restrict__ par, // s1[64], t1[64]
                                               const float* __restrict__ W2,
                                               const float* __restrict__ b2,
                                               float* __restrict__ st2,
                                               float* __restrict__ aggp) {
    __shared__ float w1s[EIN * HE_SZ];
    __shared__ float w2s[HE_SZ * OE_SZ];
    __shared__ float xs[N_ND * 33];
    __shared__ float bs[HE_SZ], s1s[HE_SZ], t1s[HE_SZ], b2s[OE_SZ];
    __shared__ float red[4 * 32];
    const int tid = threadIdx.x;
    const int b = blockIdx.x >> 3;
    const int ibase = (blockIdx.x & 7) << 4;
    for (int k = tid; k < EIN * HE_SZ; k += 256) w1s[k] = W1[k];
    for (int k = tid; k < HE_SZ * OE_SZ; k += 256) w2s[k] = W2[k];
    if (tid < HE_SZ) { bs[tid] = b1[tid]; s1s[tid] = par[tid]; t1s[tid] = par[64 + tid]; }
    if (tid < OE_SZ) b2s[tid] = b2[tid];
    const float* xg = xc + b * (N_ND * H_SZ);
#pragma unroll
    for (int r = 0; r < 16; ++r) {
        int f = r * 256 + tid;
        xs[(f >> 5) * 33 + (f & 31)] = xg[f];
    }
    __syncthreads();
    const int il = tid >> 4, j0 = tid & 15;
    float a[EIN];
    {
        const float* x1p = &xs[(ibase + il) * 33];
#pragma unroll
        for (int c = 0; c < 32; ++c) a[c] = x1p[c];
    }
    float agg[32], sq[32];
#pragma unroll
    for (int o = 0; o < 32; ++o) { agg[o] = 0.f; sq[o] = 0.f; }

    for (int e = 0; e < 8; ++e) {
        const float* x2p = &xs[(j0 + e * 16) * 33];
#pragma unroll
        for (int c = 0; c < 32; ++c) a[32 + c] = x2p[c];
        float ss = 0.f;
#pragma unroll
        for (int k = 0; k < 31; ++k) {
            float d = a[32 + k] - a[k] + 1e-12f;
            ss += d * d;
        }
        a[64] = sqrtf(ss);
        a[65] = 1.0f - (a[63] - a[31]);
        float y1n[64];
#pragma unroll
        for (int c0 = 0; c0 < 64; c0 += 4) {
            float y0 = bs[c0], y1 = bs[c0 + 1], y2 = bs[c0 + 2], y3 = bs[c0 + 3];
#pragma unroll
            for (int k = 0; k < EIN; ++k) {
                const float4 w = *(const float4*)&w1s[k * 64 + c0];
                const float av = a[k];
                y0 = fmaf(av, w.x, y0);
                y1 = fmaf(av, w.y, y1);
                y2 = fmaf(av, w.z, y2);
                y3 = fmaf(av, w.w, y3);
            }
            y0 = LRELU(y0); y1 = LRELU(y1); y2 = LRELU(y2); y3 = LRELU(y3);
            y1n[c0]     = fmaf(s1s[c0], y0, t1s[c0]);
            y1n[c0 + 1] = fmaf(s1s[c0 + 1], y1, t1s[c0 + 1]);
            y1n[c0 + 2] = fmaf(s1s[c0 + 2], y2, t1s[c0 + 2]);
            y1n[c0 + 3] = fmaf(s1s[c0 + 3], y3, t1s[c0 + 3]);
        }
#pragma unroll
        for (int o0 = 0; o0 < 32; o0 += 4) {
            float z0 = b2s[o0], z1 = b2s[o0 + 1], z2 = b2s[o0 + 2], z3 = b2s[o0 + 3];
#pragma unroll
            for (int c = 0; c < 64; ++c) {
                const float4 w = *(const float4*)&w2s[c * 32 + o0];
                const float v = y1n[c];
                z0 = fmaf(v, w.x, z0);
                z1 = fmaf(v, w.y, z1);
                z2 = fmaf(v, w.z, z2);
                z3 = fmaf(v, w.w, z3);
            }
            z0 = LRELU(z0); z1 = LRELU(z1); z2 = LRELU(z2); z3 = LRELU(z3);
            agg[o0] += z0;     sq[o0] += z0 * z0;
            agg[o0 + 1] += z1; sq[o0 + 1] += z1 * z1;
            agg[o0 + 2] += z2; sq[o0 + 2] += z2 * z2;
            agg[o0 + 3] += z3; sq[o0 + 3] += z3 * z3;
        }
    }
    // sumsq: full-wave butterfly + cross-wave + atomic
#pragma unroll
    for (int o = 0; o < 32; ++o) {
        float q = sq[o];
#pragma unroll
        for (int m = 1; m < 64; m <<= 1) q += __shfl_xor(q, m, 64);
        sq[o] = q;
    }
    const int lane = tid & 63, wid = tid >> 6;
    if (lane == 0) {
#pragma unroll
        for (int o = 0; o < 32; ++o) red[wid * 32 + o] = sq[o];
    }
    __syncthreads();
    if (tid < 32) {
        float t = red[tid] + red[32 + tid] + red[64 + tid] + red[96 + tid];
        atomicAdd(&st2[32 + tid], t);
    }
    // aggregate over j: reduce across the 16 threads sharing i_local
#pragma unroll
    for (int o = 0; o < 32; ++o) {
        float v = agg[o];
        v += __shfl_xor(v, 1, 64);
        v += __shfl_xor(v, 2, 64);
        v += __shfl_xor(v, 4, 64);
        v += __shfl_xor(v, 8, 64);
        agg[o] = v;
    }
    if (j0 == 0) {
        float* dst = &aggp[(b * N_ND + ibase + il) * 32];
#pragma unroll
        for (int o = 0; o < 32; ++o) dst[o] = agg[o];
    }
}

// ---------------- column sums of aggp -> st2[0..31] (BN2 sum for free) ------
__global__ __launch_bounds__(256) void k_sumagg(const float* __restrict__ aggp,
                                                float* __restrict__ st2) {
    __shared__ float red[4 * 32];
    const int tid = threadIdx.x;
    const int row = blockIdx.x * 256 + tid;
    const float* ap = aggp + row * 32;
    float v[32];
#pragma unroll
    for (int o = 0; o < 32; ++o) v[o] = ap[o];
#pragma unroll
    for (int o = 0; o < 32; ++o) {
        float s = v[o];
#pragma unroll
        for (int m = 1; m < 64; m <<= 1) s += __shfl_xor(s, m, 64);
        v[o] = s;
    }
    const int lane = tid & 63, wid = tid >> 6;
    if (lane == 0) {
#pragma unroll
        for (int o = 0; o < 32; ++o) red[wid * 32 + o] = v[o];
    }
    __syncthreads();
    if (tid < 32) {
        float t = red[tid] + red[32 + tid] + red[64 + tid] + red[96 + tid];
        atomicAdd(&st2[tid], t);
    }
}

// ---------------- BN finalize: st[0..n)=sum, st[n..2n)=sumsq -> s,t ----------
__global__ void k_fin(const float* __restrict__ st, int n, float cnt,
                      const float* __restrict__ g, const float* __restrict__ bt,
                      float* __restrict__ sp, float* __restrict__ tp) {
    int c = threadIdx.x;
    if (c >= n) return;
    float mu = st[c] / cnt;
    float var = st[n + c] / cnt - mu * mu;
    float inv = rsqrtf(var + BN_EPS);
    float s = g[c] * inv;
    sp[c] = s;
    tp[c] = bt[c] - mu * s;
}

// ---------------- node layer 1: h0=[BN2-fold(agg), x] @ Wn0 ----------------
__global__ __launch_bounds__(256) void k_node1(const float* __restrict__ aggp,
                                               const float* __restrict__ xc,
                                               const float* __restrict__ W,
                                               const float* __restrict__ bb,
                                               const float* __restrict__ p2, // s2[32], t2[32]
                                               float* __restrict__ hbuf,
                                               float* __restrict__ st) {
    __shared__ float wsd[64 * 32];
    __shared__ float bsd[32], s2s[32], t2s[32];
    __shared__ float red[4 * 64];
    const int tid = threadIdx.x;
    const int row = blockIdx.x * 256 + tid;
    for (int k = tid; k < 2048; k += 256) wsd[k] = W[k];
    if (tid < 32) { bsd[tid] = bb[tid]; s2s[tid] = p2[tid]; t2s[tid] = p2[32 + tid]; }
    __syncthreads();
    float h[64];
#pragma unroll
    for (int o = 0; o < 32; ++o) h[o] = fmaf(s2s[o], aggp[row * 32 + o], 128.f * t2s[o]);
#pragma unroll
    for (int c = 0; c < 32; ++c) h[32 + c] = xc[row * 32 + c];
    float v[32];
#pragma unroll
    for (int o0 = 0; o0 < 32; o0 += 4) {
        float z0 = bsd[o0], z1 = bsd[o0 + 1], z2 = bsd[o0 + 2], z3 = bsd[o0 + 3];
#pragma unroll
        for (int k = 0; k < 64; ++k) {
            const float4 w = *(const float4*)&wsd[k * 32 + o0];
            const float hv = h[k];
            z0 = fmaf(hv, w.x, z0); z1 = fmaf(hv, w.y, z1);
            z2 = fmaf(hv, w.z, z2); z3 = fmaf(hv, w.w, z3);
        }
        z0 = LRELU(z0); z1 = LRELU(z1); z2 = LRELU(z2); z3 = LRELU(z3);
        v[o0] = z0; v[o0 + 1] = z1; v[o0 + 2] = z2; v[o0 + 3] = z3;
    }
    float* hp = hbuf + row * 32;
#pragma unroll
    for (int o = 0; o < 32; ++o) hp[o] = v[o];
#pragma unroll
    for (int o = 0; o < 32; ++o) {
        float s = v[o], q = v[o] * v[o];
#pragma unroll
        for (int m = 1; m < 64; m <<= 1) {
            s += __shfl_xor(s, m, 64);
            q += __shfl_xor(q, m, 64);
        }
        v[o] = s;
        h[o] = q;  // reuse
    }
    const int lane = tid & 63, wid = tid >> 6;
    if (lane == 0) {
#pragma unroll
        for (int o = 0; o < 32; ++o) {
            red[wid * 64 + o] = v[o];
            red[wid * 64 + 32 + o] = h[o];
        }
    }
    __syncthreads();
    if (tid < 64) {
        float t = red[tid] + red[64 + tid] + red[128 + tid] + red[192 + tid];
        atomicAdd(&st[tid], t);
    }
}

// ---------------- node layer 2 (in-place on hbuf) ----------------
__global__ __launch_bounds__(256) void k_node2(float* __restrict__ hbuf,
                                               const float* __restrict__ W,
                                               const float* __restrict__ bb,
                                               const float* __restrict__ p, // sA[32], tA[32]
                                               float* __restrict__ st) {
    __shared__ float wsd[32 * 32];
    __shared__ float bsd[32], ssd[32], tsd[32];
    __shared__ float red[4 * 64];
    const int tid = threadIdx.x;
    const int row = blockIdx.x * 256 + tid;
    for (int k = tid; k < 1024; k += 256) wsd[k] = W[k];
    if (tid < 32) { bsd[tid] = bb[tid]; ssd[tid] = p[tid]; tsd[tid] = p[32 + tid]; }
    __syncthreads();
    float h[32];
#pragma unroll
    for (int c = 0; c < 32; ++c) h[c] = fmaf(ssd[c], hbuf[row * 32 + c], tsd[c]);
    float v[32];
#pragma unroll
    for (int o0 = 0; o0 < 32; o0 += 4) {
        float z0 = bsd[o0], z1 = bsd[o0 + 1], z2 = bsd[o0 + 2], z3 = bsd[o0 + 3];
#pragma unroll
        for (int k = 0; k < 32; ++k) {
            const float4 w = *(const float4*)&wsd[k * 32 + o0];
            const float hv = h[k];
            z0 = fmaf(hv, w.x, z0); z1 = fmaf(hv, w.y, z1);
            z2 = fmaf(hv, w.z, z2); z3 = fmaf(hv, w.w, z3);
        }
        z0 = LRELU(z0); z1 = LRELU(z1); z2 = LRELU(z2); z3 = LRELU(z3);
        v[o0] = z0; v[o0 + 1] = z1; v[o0 + 2] = z2; v[o0 + 3] = z3;
    }
    float* hp = hbuf + row * 32;
#pragma unroll
    for (int o = 0; o < 32; ++o) hp[o] = v[o];
#pragma unroll
    for (int o = 0; o < 32; ++o) {
        float s = v[o], q = v[o] * v[o];
#pragma unroll
        for (int m = 1; m < 64; m <<= 1) {
            s += __shfl_xor(s, m, 64);
            q += __shfl_xor(q, m, 64);
        }
        v[o] = s;
        h[o] = q;
    }
    const int lane = tid & 63, wid = tid >> 6;
    if (lane == 0) {
#pragma unroll
        for (int o = 0; o < 32; ++o) {
            red[wid * 64 + o] = v[o];
            red[wid * 64 + 32 + o] = h[o];
        }
    }
    __syncthreads();
    if (tid < 64) {
        float t = red[tid] + red[64 + tid] + red[128 + tid] + red[192 + tid];
        atomicAdd(&st[tid], t);
    }
}

// ---------------- final update: tanh(BN-fold(h) @ Wu + bu) ----------------
__global__ __launch_bounds__(256) void k_node3(const float* __restrict__ hbuf,
                                               const float* __restrict__ W,
                                               const float* __restrict__ bb,
                                               const float* __restrict__ p, // sB[32], tB[32]
                                               float* __restrict__ xout) {
    __shared__ float wsd[32 * 32];
    __shared__ float bsd[32], ssd[32], tsd[32];
    const int tid = threadIdx.x;
    const int row = blockIdx.x * 256 + tid;
    for (int k = tid; k < 1024; k += 256) wsd[k] = W[k];
    if (tid < 32) { bsd[tid] = bb[tid]; ssd[tid] = p[tid]; tsd[tid] = p[32 + tid]; }
    __syncthreads();
    float h[32];
#pragma unroll
    for (int c = 0; c < 32; ++c) h[c] = fmaf(ssd[c], hbuf[row * 32 + c], tsd[c]);
    float* xp = xout + row * 32;
#pragma unroll
    for (int o0 = 0; o0 < 32; o0 += 4) {
        float z0 = bsd[o0], z1 = bsd[o0 + 1], z2 = bsd[o0 + 2], z3 = bsd[o0 + 3];
#pragma unroll
        for (int k = 0; k < 32; ++k) {
            const float4 w = *(const float4*)&wsd[k * 32 + o0];
            const float hv = h[k];
            z0 = fmaf(hv, w.x, z0); z1 = fmaf(hv, w.y, z1);
            z2 = fmaf(hv, w.z, z2); z3 = fmaf(hv, w.w, z3);
        }
        xp[o0] = tanhf(z0);
        xp[o0 + 1] = tanhf(z1);
        xp[o0 + 2] = tanhf(z2);
        xp[o0 + 3] = tanhf(z3);
    }
}

extern "C" void kernel_launch(void* const* d_in, const int* in_sizes, int n_in,
                              void* d_out, int out_size, void* d_ws, size_t ws_size,
                              hipStream_t stream) {
    const float* x    = (const float*)d_in[0];
    const float* Wah  = (const float*)d_in[1];
    const float* bah  = (const float*)d_in[2];
    const float* Wa   = (const float*)d_in[3];
    const float* ba   = (const float*)d_in[4];
    const float* g_eh = (const float*)d_in[5];
    const float* b_eh = (const float*)d_in[6];
    const float* g_e  = (const float*)d_in[7];
    const float* b_e  = (const float*)d_in[8];
    const float* Wn0  = (const float*)d_in[9];
    const float* bn0  = (const float*)d_in[10];
    const float* Wn   = (const float*)d_in[11];
    const float* bnn  = (const float*)d_in[12];
    const float* g_n  = (const float*)d_in[13];
    const float* b_n  = (const float*)d_in[14];
    const float* Wu   = (const float*)d_in[15];
    const float* bu   = (const float*)d_in[16];

    float* ws    = (float*)d_ws;
    float* xc    = ws;               // 262144
    float* aggp  = ws + 262144;      // 262144
    float* hbuf  = ws + 524288;      // 262144
    float* stats = ws + 786432;      // 320 accum
    float* par   = stats + 320;      // 320 folded scale/shift
    float* out   = (float*)d_out;

    k_pad<<<1024, 256, 0, stream>>>(x, xc);

    for (int s = 0; s < 4; ++s) {
        hipMemsetAsync(stats, 0, 320 * sizeof(float), stream);
        k_edge1<<<512, 256, 0, stream>>>(xc, Wah + s * EIN * HE_SZ, bah + s * HE_SZ, stats);
        k_fin<<<1, 64, 0, stream>>>(stats, 64, 1048576.f, g_eh + s * 64, b_eh + s * 64,
                                    par, par + 64);
        k_edge2<<<512, 256, 0, stream>>>(xc, Wah + s * EIN * HE_SZ, bah + s * HE_SZ, par,
                                         Wa + s * HE_SZ * OE_SZ, ba + s * OE_SZ,
                                         stats + 128, aggp);
        k_sumagg<<<32, 256, 0, stream>>>(aggp, stats + 128);
        k_fin<<<1, 32, 0, stream>>>(stats + 128, 32, 1048576.f, g_e + s * 32, b_e + s * 32,
                                    par + 128, par + 160);
        k_node1<<<32, 256, 0, stream>>>(aggp, xc, Wn0 + s * 2048, bn0 + s * 32,
                                        par + 128, hbuf, stats + 192);
        k_fin<<<1, 32, 0, stream>>>(stats + 192, 32, 8192.f, g_n + s * 64, b_n + s * 64,
                                    par + 192, par + 224);
        k_node2<<<32, 256, 0, stream>>>(hbuf, Wn + s * 1024, bnn + s * 32,
                                        par + 192, stats + 256);
        k_fin<<<1, 32, 0, stream>>>(stats + 256, 32, 8192.f, g_n + s * 64 + 32,
                                    b_n + s * 64 + 32, par + 256, par + 288);
        k_node3<<<32, 256, 0, stream>>>(hbuf, Wu + s * 1024, bu + s * 32,
                                        par + 256, (s == 3) ? out : xc);
    }
}

// Round 2
// 12961.459 us; speedup vs baseline: 2.6171x; 2.6171x over previous
//
#include <hip/hip_runtime.h>
#include <hip/hip_bf16.h>

// GraphNet B=64,N=128,H=32,HE=64,OE=32,E_IN=66, 4 mp steps.
// Key algebra: edge layer1 pre-activation = P1[b,i,:] + P2[b,j,:] + dist*W1[64,:] + int*W1[65,:]
// where P1 = x@W1[0:32]+b1, P2 = x@W1[32:64]  (per-node, precomputed per step).
// dist via Gram: dist^2 = n_i + n_j - 2*dot(x_i',x_j')  (31 dims; eps 1e-12 negligible).

#define ALPHA 0.1f
#define BN_EPS 1e-5f
#define LRELU(v) ((v) > 0.f ? (v) : ALPHA * (v))

// ---------------- pad input [B,N,3] -> [B,N,32] ----------------
__global__ __launch_bounds__(256) void k_pad(const float* __restrict__ x,
                                             float* __restrict__ xc) {
    int idx = blockIdx.x * 256 + threadIdx.x;   // 262144
    int c = idx & 31;
    int bn = idx >> 5;
    xc[idx] = (c < 3) ? x[bn * 3 + c] : 0.f;
}

// ---------------- per-node precompute: P1, P2, {norm, xlast} ----------------
// grid 64 x 256: gid -> row = gid>>1 (8192 rows), half = gid&1 (32-col half)
__global__ __launch_bounds__(256) void k_prep(const float* __restrict__ xc,
                                              const float* __restrict__ W1,
                                              const float* __restrict__ b1,
                                              float* __restrict__ P1,
                                              float* __restrict__ P2,
                                              float2* __restrict__ nbuf) {
    __shared__ float w1s[4096];  // W1 rows 0..63
    const int tid = threadIdx.x;
    for (int k = tid; k < 4096; k += 256) w1s[k] = W1[k];
    __syncthreads();
    const int gid = blockIdx.x * 256 + tid;
    const int row = gid >> 1, half = gid & 1;
    float xr[32];
    const float4* xp = (const float4*)(xc + row * 32);
#pragma unroll
    for (int u = 0; u < 8; ++u) {
        float4 v = xp[u];
        xr[4*u] = v.x; xr[4*u+1] = v.y; xr[4*u+2] = v.z; xr[4*u+3] = v.w;
    }
    if (!half) {
        float n = 0.f;
#pragma unroll
        for (int k = 0; k < 31; ++k) n = fmaf(xr[k], xr[k], n);
        nbuf[row] = make_float2(n, xr[31]);
    }
    const int cb = half * 32;
#pragma unroll
    for (int c0 = 0; c0 < 32; c0 += 4) {
        const int c = cb + c0;
        float a0 = b1[c], a1 = b1[c+1], a2 = b1[c+2], a3 = b1[c+3];
        float q0 = 0.f, q1 = 0.f, q2 = 0.f, q3 = 0.f;
#pragma unroll
        for (int k = 0; k < 32; ++k) {
            const float xv = xr[k];
            const float4 wa = *(const float4*)&w1s[k * 64 + c];
            const float4 wb = *(const float4*)&w1s[(32 + k) * 64 + c];
            a0 = fmaf(xv, wa.x, a0); a1 = fmaf(xv, wa.y, a1);
            a2 = fmaf(xv, wa.z, a2); a3 = fmaf(xv, wa.w, a3);
            q0 = fmaf(xv, wb.x, q0); q1 = fmaf(xv, wb.y, q1);
            q2 = fmaf(xv, wb.z, q2); q3 = fmaf(xv, wb.w, q3);
        }
        float* p1p = P1 + row * 64 + c;
        p1p[0] = a0; p1p[1] = a1; p1p[2] = a2; p1p[3] = a3;
        float* p2p = P2 + row * 64 + c;
        p2p[0] = q0; p2p[1] = q1; p2p[2] = q2; p2p[3] = q3;
    }
}

// ---------------- edge pass 1: BN1 stats of lrelu(layer1) ----------------
// grid 1024 = b(64) x itile(16, 8 i's each). 256 threads.
// thread: cg = tid&3 (16 cols), eg = tid>>2; 16 edges each.
__global__ __launch_bounds__(256) void k_edge1(const float* __restrict__ xc,
                                               const float2* __restrict__ nbuf,
                                               const float* __restrict__ P1,
                                               const float* __restrict__ P2,
                                               const float* __restrict__ W1,
                                               float* __restrict__ stA) {
    __shared__ float xs[128 * 33];
    __shared__ float ddot[1024];
    __shared__ float2 nls[128];
    __shared__ float red[512];
    const int tid = threadIdx.x;
    const int b = blockIdx.x >> 4;
    const int ibase = (blockIdx.x & 15) * 8;
    const float* xg = xc + b * 4096;
    for (int u = tid; u < 4096; u += 256) xs[(u >> 5) * 33 + (u & 31)] = xg[u];
    if (tid < 128) nls[tid] = nbuf[b * 128 + tid];
    __syncthreads();
    {   // dot phase: ddot[il][j] = dot(x[ibase+il,0:31], x[j,0:31])
        const int il = tid >> 5, jb = tid & 31;
        const float* xi = &xs[(ibase + il) * 33];
        float xi_r[31];
#pragma unroll
        for (int k = 0; k < 31; ++k) xi_r[k] = xi[k];
        for (int q = 0; q < 4; ++q) {
            const int j = jb + 32 * q;
            const float* xj = &xs[j * 33];
            float d = 0.f;
#pragma unroll
            for (int k = 0; k < 31; ++k) d = fmaf(xi_r[k], xj[k], d);
            ddot[il * 128 + j] = d;
        }
    }
    __syncthreads();
    const int cg = tid & 3, eg = tid >> 2;
    float w64r[16], w65r[16];
    {
        const float* wg4 = W1 + 64 * 64 + cg * 16;
        const float* wg5 = W1 + 65 * 64 + cg * 16;
#pragma unroll
        for (int u = 0; u < 4; ++u) {
            float4 v = *(const float4*)(wg4 + u * 4);
            w64r[4*u] = v.x; w64r[4*u+1] = v.y; w64r[4*u+2] = v.z; w64r[4*u+3] = v.w;
            float4 w = *(const float4*)(wg5 + u * 4);
            w65r[4*u] = w.x; w65r[4*u+1] = w.y; w65r[4*u+2] = w.z; w65r[4*u+3] = w.w;
        }
    }
    float sum[16], sq[16];
#pragma unroll
    for (int u = 0; u < 16; ++u) { sum[u] = 0.f; sq[u] = 0.f; }
    for (int ei = 0; ei < 16; ++ei) {
        const int eid = eg + 64 * ei;          // il wave-uniform
        const int il = eid >> 7, j = eid & 127;
        const float2 nj = nls[j];
        const float2 ni = nls[ibase + il];
        const float dot = ddot[il * 128 + j];
        const float dist = sqrtf(fmaxf(ni.x + nj.x - 2.f * dot, 0.f));
        const float itf = 1.f - (nj.y - ni.y);
        const int prow = __builtin_amdgcn_readfirstlane((b * 128 + ibase + il) * 64) + cg * 16;
        const float* p2row = P2 + (b * 128 + j) * 64 + cg * 16;
#pragma unroll
        for (int u = 0; u < 4; ++u) {
            const float4 p1v = *(const float4*)(P1 + prow + u * 4);
            const float4 p2v = *(const float4*)(p2row + u * 4);
            float y0 = fmaf(itf, w65r[4*u+0], fmaf(dist, w64r[4*u+0], p1v.x + p2v.x));
            float y1 = fmaf(itf, w65r[4*u+1], fmaf(dist, w64r[4*u+1], p1v.y + p2v.y));
            float y2 = fmaf(itf, w65r[4*u+2], fmaf(dist, w64r[4*u+2], p1v.z + p2v.z));
            float y3 = fmaf(itf, w65r[4*u+3], fmaf(dist, w64r[4*u+3], p1v.w + p2v.w));
            y0 = LRELU(y0); y1 = LRELU(y1); y2 = LRELU(y2); y3 = LRELU(y3);
            sum[4*u+0] += y0; sq[4*u+0] += y0 * y0;
            sum[4*u+1] += y1; sq[4*u+1] += y1 * y1;
            sum[4*u+2] += y2; sq[4*u+2] += y2 * y2;
            sum[4*u+3] += y3; sq[4*u+3] += y3 * y3;
        }
    }
    // reduce over eg within wave (bits 2..5), keep cg
#pragma unroll
    for (int u = 0; u < 16; ++u) {
        float s = sum[u], q = sq[u];
#pragma unroll
        for (int m = 4; m < 64; m <<= 1) { s += __shfl_xor(s, m, 64); q += __shfl_xor(q, m, 64); }
        sum[u] = s; sq[u] = q;
    }
    const int l = tid & 63, w = tid >> 6;
#pragma unroll
    for (int k = 0; k < 16; ++k) {
        if ((l >> 2) == k) {
            red[w * 128 + cg * 32 + k] = sum[k];
            red[w * 128 + cg * 32 + 16 + k] = sq[k];
        }
    }
    __syncthreads();
    if (tid < 128) {
        const float t = red[tid] + red[128 + tid] + red[256 + tid] + red[384 + tid];
        const int cgf = tid >> 5, r = tid & 31;
        if (r < 16) atomicAdd(stA + cgf * 16 + r, t);
        else        atomicAdd(stA + 64 + cgf * 16 + (r - 16), t);
    }
}

// ---------------- edge pass 2: rebuild layer1, BN1-fold, GEMM2, aggregate ----------------
// grid 1024 as edge1. thread: wave w handles il = w, w+4; lane l covers j = l, l+64.
__global__ __launch_bounds__(256) void k_edge2(const float* __restrict__ xc,
                                               const float2* __restrict__ nbuf,
                                               const float* __restrict__ P1,
                                               const float* __restrict__ P2,
                                               const float* __restrict__ W1,
                                               const float* __restrict__ W2,
                                               const float* __restrict__ b2g,
                                               const float* __restrict__ g1,
                                               const float* __restrict__ bt1,
                                               const float* __restrict__ stA,
                                               float* __restrict__ stB,
                                               float* __restrict__ aggp) {
    __shared__ float xs[128 * 33];
    __shared__ float ddot[1024];
    __shared__ float2 nls[128];
    __shared__ float w2s[2048];
    __shared__ float s1s[64], t1s[64], w64s[64], w65s[64], b2s[32];
    __shared__ float aggl[256];
    __shared__ float redq[128];
    const int tid = threadIdx.x;
    const int b = blockIdx.x >> 4;
    const int ibase = (blockIdx.x & 15) * 8;
    const float* xg = xc + b * 4096;
    for (int u = tid; u < 4096; u += 256) xs[(u >> 5) * 33 + (u & 31)] = xg[u];
    for (int u = tid; u < 2048; u += 256) w2s[u] = W2[u];
    if (tid < 128) nls[tid] = nbuf[b * 128 + tid];
    if (tid < 64) {
        const float ic = 1.f / 1048576.f;
        const float mu = stA[tid] * ic;
        const float var = stA[64 + tid] * ic - mu * mu;
        const float sv = g1[tid] * rsqrtf(var + BN_EPS);
        s1s[tid] = sv;
        t1s[tid] = bt1[tid] - mu * sv;
        w64s[tid] = W1[64 * 64 + tid];
        w65s[tid] = W1[65 * 64 + tid];
    }
    if (tid < 32) b2s[tid] = b2g[tid];
    __syncthreads();
    {   // dot phase
        const int il = tid >> 5, jb = tid & 31;
        const float* xi = &xs[(ibase + il) * 33];
        float xi_r[31];
#pragma unroll
        for (int k = 0; k < 31; ++k) xi_r[k] = xi[k];
        for (int q = 0; q < 4; ++q) {
            const int j = jb + 32 * q;
            const float* xj = &xs[j * 33];
            float d = 0.f;
#pragma unroll
            for (int k = 0; k < 31; ++k) d = fmaf(xi_r[k], xj[k], d);
            ddot[il * 128 + j] = d;
        }
    }
    __syncthreads();
    const int w = tid >> 6, l = tid & 63;
    float sqa[32];
#pragma unroll
    for (int c = 0; c < 32; ++c) sqa[c] = 0.f;
    for (int q = 0; q < 2; ++q) {
        const int il = w + 4 * q;               // wave-uniform
        const int prow = __builtin_amdgcn_readfirstlane((b * 128 + ibase + il) * 64);
        const float2 ni = nls[ibase + il];
        float agg[32];
#pragma unroll
        for (int c = 0; c < 32; ++c) agg[c] = 0.f;
        for (int r = 0; r < 2; ++r) {
            const int j = l + 64 * r;
            const float2 nj = nls[j];
            const float dot = ddot[il * 128 + j];
            const float dist = sqrtf(fmaxf(ni.x + nj.x - 2.f * dot, 0.f));
            const float itf = 1.f - (nj.y - ni.y);
            float y1n[64];
            const float* p2row = P2 + (b * 128 + j) * 64;
#pragma unroll
            for (int c0 = 0; c0 < 64; c0 += 4) {
                const float4 p1v = *(const float4*)(P1 + prow + c0);
                const float4 p2v = *(const float4*)(p2row + c0);
                const float4 wa = *(const float4*)&w64s[c0];
                const float4 wb = *(const float4*)&w65s[c0];
                const float4 s1 = *(const float4*)&s1s[c0];
                const float4 t1 = *(const float4*)&t1s[c0];
                float y0 = fmaf(itf, wb.x, fmaf(dist, wa.x, p1v.x + p2v.x));
                float y1 = fmaf(itf, wb.y, fmaf(dist, wa.y, p1v.y + p2v.y));
                float y2 = fmaf(itf, wb.z, fmaf(dist, wa.z, p1v.z + p2v.z));
                float y3 = fmaf(itf, wb.w, fmaf(dist, wa.w, p1v.w + p2v.w));
                y0 = LRELU(y0); y1 = LRELU(y1); y2 = LRELU(y2); y3 = LRELU(y3);
                y1n[c0+0] = fmaf(s1.x, y0, t1.x);
                y1n[c0+1] = fmaf(s1.y, y1, t1.y);
                y1n[c0+2] = fmaf(s1.z, y2, t1.z);
                y1n[c0+3] = fmaf(s1.w, y3, t1.w);
            }
#pragma unroll
            for (int c0 = 0; c0 < 32; c0 += 4) {
                float z0 = b2s[c0+0], z1 = b2s[c0+1], z2 = b2s[c0+2], z3 = b2s[c0+3];
#pragma unroll
                for (int k = 0; k < 64; ++k) {
                    const float4 wv = *(const float4*)&w2s[k * 32 + c0];
                    const float yv = y1n[k];
                    z0 = fmaf(yv, wv.x, z0); z1 = fmaf(yv, wv.y, z1);
                    z2 = fmaf(yv, wv.z, z2); z3 = fmaf(yv, wv.w, z3);
                }
                z0 = LRELU(z0); z1 = LRELU(z1); z2 = LRELU(z2); z3 = LRELU(z3);
                agg[c0+0] += z0; sqa[c0+0] += z0 * z0;
                agg[c0+1] += z1; sqa[c0+1] += z1 * z1;
                agg[c0+2] += z2; sqa[c0+2] += z2 * z2;
                agg[c0+3] += z3; sqa[c0+3] += z3 * z3;
            }
        }
        // full-wave reduce (lanes cover all 128 j for this il)
#pragma unroll
        for (int c = 0; c < 32; ++c) {
            float v = agg[c];
#pragma unroll
            for (int m = 1; m < 64; m <<= 1) v += __shfl_xor(v, m, 64);
            agg[c] = v;
        }
#pragma unroll
        for (int c = 0; c < 32; ++c) if (l == c) aggl[il * 32 + c] = agg[c];
    }
#pragma unroll
    for (int c = 0; c < 32; ++c) {
        float v = sqa[c];
#pragma unroll
        for (int m = 1; m < 64; m <<= 1) v += __shfl_xor(v, m, 64);
        sqa[c] = v;
    }
#pragma unroll
    for (int c = 0; c < 32; ++c) if (l == c) redq[w * 32 + c] = sqa[c];
    __syncthreads();
    {
        const int il2 = tid >> 5, c2 = tid & 31;
        aggp[(b * 128 + ibase + il2) * 32 + c2] = aggl[il2 * 32 + c2];
    }
    if (tid < 32) {
        float s = 0.f;
#pragma unroll
        for (int il3 = 0; il3 < 8; ++il3) s += aggl[il3 * 32 + tid];
        atomicAdd(stB + tid, s);
        const float qq = redq[tid] + redq[32 + tid] + redq[64 + tid] + redq[96 + tid];
        atomicAdd(stB + 32 + tid, qq);
    }
}

// ---------------- node layer 1 (BN2-fold + GEMM + stats) ----------------
__global__ __launch_bounds__(256) void k_node1(const float* __restrict__ aggp,
                                               const float* __restrict__ xc,
                                               const float* __restrict__ W,
                                               const float* __restrict__ bb,
                                               const float* __restrict__ stB,
                                               const float* __restrict__ g2,
                                               const float* __restrict__ bt2,
                                               float* __restrict__ hbuf,
                                               float* __restrict__ stC) {
    __shared__ float wsd[2048];
    __shared__ float bsd[32], s2s[32], t2s[32];
    __shared__ float red[256];
    const int tid = threadIdx.x;
    const int row = blockIdx.x * 256 + tid;
    for (int k = tid; k < 2048; k += 256) wsd[k] = W[k];
    if (tid < 32) {
        bsd[tid] = bb[tid];
        const float ic = 1.f / 1048576.f;
        const float mu = stB[tid] * ic;
        const float var = stB[32 + tid] * ic - mu * mu;
        const float sv = g2[tid] * rsqrtf(var + BN_EPS);
        s2s[tid] = sv; t2s[tid] = bt2[tid] - mu * sv;
    }
    __syncthreads();
    float h[64];
    {
        const float4* ap = (const float4*)(aggp + row * 32);
        const float4* xp = (const float4*)(xc + row * 32);
#pragma unroll
        for (int u = 0; u < 8; ++u) {
            const float4 a = ap[u];
            h[4*u+0] = fmaf(s2s[4*u+0], a.x, 128.f * t2s[4*u+0]);
            h[4*u+1] = fmaf(s2s[4*u+1], a.y, 128.f * t2s[4*u+1]);
            h[4*u+2] = fmaf(s2s[4*u+2], a.z, 128.f * t2s[4*u+2]);
            h[4*u+3] = fmaf(s2s[4*u+3], a.w, 128.f * t2s[4*u+3]);
            const float4 xv = xp[u];
            h[32+4*u+0] = xv.x; h[32+4*u+1] = xv.y; h[32+4*u+2] = xv.z; h[32+4*u+3] = xv.w;
        }
    }
    float v[32];
#pragma unroll
    for (int o0 = 0; o0 < 32; o0 += 4) {
        float z0 = bsd[o0], z1 = bsd[o0+1], z2 = bsd[o0+2], z3 = bsd[o0+3];
#pragma unroll
        for (int k = 0; k < 64; ++k) {
            const float4 wv = *(const float4*)&wsd[k * 32 + o0];
            const float hv = h[k];
            z0 = fmaf(hv, wv.x, z0); z1 = fmaf(hv, wv.y, z1);
            z2 = fmaf(hv, wv.z, z2); z3 = fmaf(hv, wv.w, z3);
        }
        z0 = LRELU(z0); z1 = LRELU(z1); z2 = LRELU(z2); z3 = LRELU(z3);
        v[o0] = z0; v[o0+1] = z1; v[o0+2] = z2; v[o0+3] = z3;
    }
    float* hp = hbuf + row * 32;
#pragma unroll
    for (int o = 0; o < 32; ++o) hp[o] = v[o];
#pragma unroll
    for (int o = 0; o < 32; ++o) {
        float s = v[o], q = v[o] * v[o];
#pragma unroll
        for (int m = 1; m < 64; m <<= 1) { s += __shfl_xor(s, m, 64); q += __shfl_xor(q, m, 64); }
        v[o] = s; h[o] = q;
    }
    const int lane = tid & 63, wid = tid >> 6;
    if (lane == 0) {
#pragma unroll
        for (int o = 0; o < 32; ++o) { red[wid * 64 + o] = v[o]; red[wid * 64 + 32 + o] = h[o]; }
    }
    __syncthreads();
    if (tid < 64) {
        const float t = red[tid] + red[64 + tid] + red[128 + tid] + red[192 + tid];
        atomicAdd(stC + tid, t);
    }
}

// ---------------- node layer 2 (BN-fold + GEMM + stats, in-place) ----------------
__global__ __launch_bounds__(256) void k_node2(float* __restrict__ hbuf,
                                               const float* __restrict__ W,
                                               const float* __restrict__ bb,
                                               const float* __restrict__ stC,
                                               const float* __restrict__ g,
                                               const float* __restrict__ bt,
                                               float* __restrict__ stD) {
    __shared__ float wsd[1024];
    __shared__ float bsd[32], ssd[32], tsd[32];
    __shared__ float red[256];
    const int tid = threadIdx.x;
    const int row = blockIdx.x * 256 + tid;
    for (int k = tid; k < 1024; k += 256) wsd[k] = W[k];
    if (tid < 32) {
        bsd[tid] = bb[tid];
        const float ic = 1.f / 8192.f;
        const float mu = stC[tid] * ic;
        const float var = stC[32 + tid] * ic - mu * mu;
        const float sv = g[tid] * rsqrtf(var + BN_EPS);
        ssd[tid] = sv; tsd[tid] = bt[tid] - mu * sv;
    }
    __syncthreads();
    float h[32];
    {
        const float4* hp4 = (const float4*)(hbuf + row * 32);
#pragma unroll
        for (int u = 0; u < 8; ++u) {
            const float4 x = hp4[u];
            h[4*u+0] = fmaf(ssd[4*u+0], x.x, tsd[4*u+0]);
            h[4*u+1] = fmaf(ssd[4*u+1], x.y, tsd[4*u+1]);
            h[4*u+2] = fmaf(ssd[4*u+2], x.z, tsd[4*u+2]);
            h[4*u+3] = fmaf(ssd[4*u+3], x.w, tsd[4*u+3]);
        }
    }
    float v[32];
#pragma unroll
    for (int o0 = 0; o0 < 32; o0 += 4) {
        float z0 = bsd[o0], z1 = bsd[o0+1], z2 = bsd[o0+2], z3 = bsd[o0+3];
#pragma unroll
        for (int k = 0; k < 32; ++k) {
            const float4 wv = *(const float4*)&wsd[k * 32 + o0];
            const float hv = h[k];
            z0 = fmaf(hv, wv.x, z0); z1 = fmaf(hv, wv.y, z1);
            z2 = fmaf(hv, wv.z, z2); z3 = fmaf(hv, wv.w, z3);
        }
        z0 = LRELU(z0); z1 = LRELU(z1); z2 = LRELU(z2); z3 = LRELU(z3);
        v[o0] = z0; v[o0+1] = z1; v[o0+2] = z2; v[o0+3] = z3;
    }
    float* hp = hbuf + row * 32;
#pragma unroll
    for (int o = 0; o < 32; ++o) hp[o] = v[o];
#pragma unroll
    for (int o = 0; o < 32; ++o) {
        float s = v[o], q = v[o] * v[o];
#pragma unroll
        for (int m = 1; m < 64; m <<= 1) { s += __shfl_xor(s, m, 64); q += __shfl_xor(q, m, 64); }
        v[o] = s; h[o] = q;
    }
    const int lane = tid & 63, wid = tid >> 6;
    if (lane == 0) {
#pragma unroll
        for (int o = 0; o < 32; ++o) { red[wid * 64 + o] = v[o]; red[wid * 64 + 32 + o] = h[o]; }
    }
    __syncthreads();
    if (tid < 64) {
        const float t = red[tid] + red[64 + tid] + red[128 + tid] + red[192 + tid];
        atomicAdd(stD + tid, t);
    }
}

// ---------------- final: BN-fold + GEMM(Wu) + tanh ----------------
__global__ __launch_bounds__(256) void k_node3(const float* __restrict__ hbuf,
                                               const float* __restrict__ W,
                                               const float* __restrict__ bb,
                                               const float* __restrict__ stD,
                                               const float* __restrict__ g,
                                               const float* __restrict__ bt,
                                               float* __restrict__ xout) {
    __shared__ float wsd[1024];
    __shared__ float bsd[32], ssd[32], tsd[32];
    const int tid = threadIdx.x;
    const int row = blockIdx.x * 256 + tid;
    for (int k = tid; k < 1024; k += 256) wsd[k] = W[k];
    if (tid < 32) {
        bsd[tid] = bb[tid];
        const float ic = 1.f / 8192.f;
        const float mu = stD[tid] * ic;
        const float var = stD[32 + tid] * ic - mu * mu;
        const float sv = g[tid] * rsqrtf(var + BN_EPS);
        ssd[tid] = sv; tsd[tid] = bt[tid] - mu * sv;
    }
    __syncthreads();
    float h[32];
    {
        const float4* hp4 = (const float4*)(hbuf + row * 32);
#pragma unroll
        for (int u = 0; u < 8; ++u) {
            const float4 x = hp4[u];
            h[4*u+0] = fmaf(ssd[4*u+0], x.x, tsd[4*u+0]);
            h[4*u+1] = fmaf(ssd[4*u+1], x.y, tsd[4*u+1]);
            h[4*u+2] = fmaf(ssd[4*u+2], x.z, tsd[4*u+2]);
            h[4*u+3] = fmaf(ssd[4*u+3], x.w, tsd[4*u+3]);
        }
    }
    float* xp = xout + row * 32;
#pragma unroll
    for (int o0 = 0; o0 < 32; o0 += 4) {
        float z0 = bsd[o0], z1 = bsd[o0+1], z2 = bsd[o0+2], z3 = bsd[o0+3];
#pragma unroll
        for (int k = 0; k < 32; ++k) {
            const float4 wv = *(const float4*)&wsd[k * 32 + o0];
            const float hv = h[k];
            z0 = fmaf(hv, wv.x, z0); z1 = fmaf(hv, wv.y, z1);
            z2 = fmaf(hv, wv.z, z2); z3 = fmaf(hv, wv.w, z3);
        }
        xp[o0]   = tanhf(z0);
        xp[o0+1] = tanhf(z1);
        xp[o0+2] = tanhf(z2);
        xp[o0+3] = tanhf(z3);
    }
}

extern "C" void kernel_launch(void* const* d_in, const int* in_sizes, int n_in,
                              void* d_out, int out_size, void* d_ws, size_t ws_size,
                              hipStream_t stream) {
    const float* x    = (const float*)d_in[0];
    const float* Wah  = (const float*)d_in[1];
    const float* bah  = (const float*)d_in[2];
    const float* Wa   = (const float*)d_in[3];
    const float* ba   = (const float*)d_in[4];
    const float* g_eh = (const float*)d_in[5];
    const float* b_eh = (const float*)d_in[6];
    const float* g_e  = (const float*)d_in[7];
    const float* b_e  = (const float*)d_in[8];
    const float* Wn0  = (const float*)d_in[9];
    const float* bn0  = (const float*)d_in[10];
    const float* Wn   = (const float*)d_in[11];
    const float* bnn  = (const float*)d_in[12];
    const float* g_n  = (const float*)d_in[13];
    const float* b_n  = (const float*)d_in[14];
    const float* Wu   = (const float*)d_in[15];
    const float* bu   = (const float*)d_in[16];

    float* ws    = (float*)d_ws;
    float* xc    = ws;                 // 262144
    float* aggp  = ws + 262144;        // 262144
    float* hbuf  = ws + 524288;        // 262144
    float* P1    = ws + 786432;        // 524288
    float* P2    = ws + 1310720;       // 524288
    float2* nbuf = (float2*)(ws + 1835008);  // 16384 float2
    float* stats = ws + 1867776;       // 1280 (320/step)
    float* out   = (float*)d_out;

    k_pad<<<1024, 256, 0, stream>>>(x, xc);
    hipMemsetAsync(stats, 0, 1280 * sizeof(float), stream);

    for (int s = 0; s < 4; ++s) {
        const float* W1 = Wah + s * 66 * 64;
        const float* b1 = bah + s * 64;
        const float* W2 = Wa + s * 64 * 32;
        const float* b2 = ba + s * 32;
        float* stA = stats + s * 320;
        float* stB = stA + 128;
        float* stC = stA + 192;
        float* stD = stA + 256;

        k_prep<<<64, 256, 0, stream>>>(xc, W1, b1, P1, P2, nbuf);
        k_edge1<<<1024, 256, 0, stream>>>(xc, nbuf, P1, P2, W1, stA);
        k_edge2<<<1024, 256, 0, stream>>>(xc, nbuf, P1, P2, W1, W2, b2,
                                          g_eh + s * 64, b_eh + s * 64, stA, stB, aggp);
        k_node1<<<32, 256, 0, stream>>>(aggp, xc, Wn0 + s * 2048, bn0 + s * 32,
                                        stB, g_e + s * 32, b_e + s * 32, hbuf, stC);
        k_node2<<<32, 256, 0, stream>>>(hbuf, Wn + s * 1024, bnn + s * 32,
                                        stC, g_n + s * 64, b_n + s * 64, stD);
        k_node3<<<32, 256, 0, stream>>>(hbuf, Wu + s * 1024, bu + s * 32,
                                        stD, g_n + s * 64 + 32, b_n + s * 64 + 32,
                                        (s == 3) ? out : xc);
    }
}